// Round 10
// baseline (106.877 us; speedup 1.0000x reference)
//
#include <hip/hip_runtime.h>
#include <hip/hip_bf16.h>
#include <stdint.h>

#define B_ 8
#define N_ 2048
#define F_ 128
#define D_ 128

typedef short bf16x8 __attribute__((ext_vector_type(8)));
typedef float f32x4 __attribute__((ext_vector_type(4)));

__device__ __forceinline__ unsigned short f2bf(float f) {
    unsigned u = __float_as_uint(f);
    u += 0x7fffu + ((u >> 16) & 1u);
    return (unsigned short)(u >> 16);
}

// ---------------- Kernel 1: degrees -> rsqrt  (+ W transpose in tail blocks) ----------------
__global__ __launch_bounds__(256) void k_degwt(const float* __restrict__ adj,
                                               const float* __restrict__ W,
                                               float* __restrict__ rs,
                                               unsigned short* __restrict__ Wt) {
    if (blockIdx.x < 4096) {
        const int wave = threadIdx.x >> 6, lane = threadIdx.x & 63;
        const int row = blockIdx.x * 4 + wave;          // 0..B_*N_-1
        const float4* p = (const float4*)(adj + (size_t)row * N_);
        float s = 0.f;
#pragma unroll
        for (int j = 0; j < 8; ++j) {
            float4 v = p[j * 64 + lane];
            s += (v.x + v.y) + (v.z + v.w);
        }
#pragma unroll
        for (int m = 1; m < 64; m <<= 1) s += __shfl_xor(s, m, 64);
        if (lane == 0) rs[row] = (s > 0.f) ? (1.0f / sqrtf(s)) : 0.f;
    } else {
        int c = (blockIdx.x - 4096) * 256 + threadIdx.x;
        int d = c >> 4, f0 = (c & 15) * 8;
        union { bf16x8 v; unsigned short u[8]; } pk;
#pragma unroll
        for (int e = 0; e < 8; ++e) pk.u[e] = f2bf(W[(size_t)(f0 + e) * D_ + d]);
        *(bf16x8*)(Wt + (size_t)d * F_ + f0) = pk.v;
    }
}

// ---------------- Kernel 2: gt[b][d][m] = rs[m]*(X@W + bias)^T, bf16 (pre-scaled) ----------------
__global__ __launch_bounds__(256) void k_feat(const float* __restrict__ x,
                                              const unsigned short* __restrict__ Wt,
                                              const float* __restrict__ bias,
                                              const float* __restrict__ rs,
                                              unsigned short* __restrict__ gt) {
    __shared__ __align__(16) unsigned char sX[64 * 128 * 2];
    __shared__ __align__(16) unsigned char sW[128 * 128 * 2];
    const int t = threadIdx.x;
    const int R0 = blockIdx.x * 64;

#pragma unroll
    for (int j = 0; j < 8; ++j) {
        int c = j * 256 + t;
        unsigned L = (unsigned)c * 16u;
        unsigned lg = L ^ (((L >> 8) & 7u) << 4);
        const unsigned char* src = (const unsigned char*)Wt + lg;
        __builtin_amdgcn_global_load_lds(
            (const __attribute__((address_space(1))) void*)src,
            (__attribute__((address_space(3))) void*)(sW + L), 16, 0, 0);
    }
#pragma unroll
    for (int j = 0; j < 4; ++j) {
        int c = j * 256 + t;
        int row = c >> 4, sub = c & 15;
        const float4* src = (const float4*)(x + (size_t)(R0 + row) * F_ + sub * 8);
        float4 v0 = src[0], v1 = src[1];
        union { bf16x8 v; unsigned short u[8]; } pk;
        pk.u[0] = f2bf(v0.x); pk.u[1] = f2bf(v0.y); pk.u[2] = f2bf(v0.z); pk.u[3] = f2bf(v0.w);
        pk.u[4] = f2bf(v1.x); pk.u[5] = f2bf(v1.y); pk.u[6] = f2bf(v1.z); pk.u[7] = f2bf(v1.w);
        unsigned byte = (unsigned)(row * 256 + sub * 16);
        byte ^= ((byte >> 8) & 7u) << 4;
        *(bf16x8*)(sX + byte) = pk.v;
    }
    __syncthreads();

    const int w = t >> 6, l = t & 63, lr = l & 15, lh = l >> 4;
    f32x4 acc[8];
#pragma unroll
    for (int j = 0; j < 8; ++j) acc[j] = (f32x4){0.f, 0.f, 0.f, 0.f};

#pragma unroll
    for (int ks = 0; ks < 4; ++ks) {
        unsigned abyte = (unsigned)((w * 16 + lr) * 256 + lh * 16 + ks * 64);
        abyte ^= ((abyte >> 8) & 7u) << 4;
        bf16x8 a = *(const bf16x8*)(sX + abyte);
#pragma unroll
        for (int j = 0; j < 8; ++j) {
            unsigned bbyte = (unsigned)((j * 16 + lr) * 256 + lh * 16 + ks * 64);
            bbyte ^= ((bbyte >> 8) & 7u) << 4;
            bf16x8 bb = *(const bf16x8*)(sW + bbyte);
            acc[j] = __builtin_amdgcn_mfma_f32_16x16x32_bf16(a, bb, acc[j], 0, 0, 0);
        }
    }

    const int m0 = R0 + w * 16 + lh * 4;
    float4 r4 = *(const float4*)(rs + m0);
    float rr[4] = {r4.x, r4.y, r4.z, r4.w};
#pragma unroll
    for (int j = 0; j < 8; ++j) {
        int d = j * 16 + lr;
        float bv = bias[d];
#pragma unroll
        for (int r = 0; r < 4; ++r) {
            int m = m0 + r;
            int b = m >> 11, n = m & (N_ - 1);
            gt[((size_t)b * D_ + d) * N_ + n] = f2bf((acc[j][r] + bv) * rr[r]);
        }
    }
}

// ---------------- Kernel 3: out = relu(rs[n] * (adj @ gt^T)) ----------------
// R9 body, unchanged. Launched 3x this round to measure T_gcn differentially.
__global__ __launch_bounds__(512) void k_gcn(const float* __restrict__ adj,
                                             const unsigned short* __restrict__ gt,
                                             const float* __restrict__ rs,
                                             float* __restrict__ out) {
    __shared__ __align__(16) unsigned char sA[2][32 * 256];    // 2 x 8 KB bf16
    __shared__ __align__(16) unsigned char sB[2][128 * 256];   // 2 x 32 KB bf16 (80 KB total)

    unsigned bid = blockIdx.x;
    unsigned wg = (bid & 7u) * 64u + (bid >> 3);
    const int b = (int)(wg >> 6);
    const int R0 = (int)(wg & 63u) * 32;

    const float* adjB = adj + (size_t)(b * N_ + R0) * N_;
    const unsigned short* gtB = gt + (size_t)b * D_ * N_;
    const float* rsB = rs + (size_t)b * N_;

    const int t = threadIdx.x;
    const int w = t >> 6, l = t & 63, lr = l & 15, lh = l >> 4;
    const int kg = w >> 2, cg = w & 3;

    const float* aSrc = adjB + (size_t)(t >> 4) * N_ + (t & 15) * 8;
    unsigned aL = (unsigned)((t >> 4) * 256 + (t & 15) * 16);
    aL ^= (((unsigned)(t >> 4) & 7u) << 4);

    const unsigned short* bSrc[4];
    unsigned bL[4];
#pragma unroll
    for (int i = 0; i < 4; ++i) {
        unsigned c = (unsigned)(i * 512 + t);
        unsigned L = c * 16u;
        unsigned lg = L ^ (((L >> 8) & 7u) << 4);
        bL[i] = L;
        bSrc[i] = gtB + (size_t)(lg >> 8) * N_ + ((lg & 255u) >> 1);
    }
    auto issueB = [&](int buf, int k0) {
        unsigned char* pB = sB[buf];
#pragma unroll
        for (int i = 0; i < 4; ++i) {
            __builtin_amdgcn_global_load_lds(
                (const __attribute__((address_space(1))) void*)(bSrc[i] + k0),
                (__attribute__((address_space(3))) void*)(pB + bL[i]), 16, 0, 0);
        }
    };
    auto cvtWrite = [&](int buf, const f32x4& x0, const f32x4& x1) {
        unsigned u0, u1, u2, u3;
        asm("v_cvt_pk_bf16_f32 %0, %1, %2" : "=v"(u0) : "v"(x0[0]), "v"(x0[1]));
        asm("v_cvt_pk_bf16_f32 %0, %1, %2" : "=v"(u1) : "v"(x0[2]), "v"(x0[3]));
        asm("v_cvt_pk_bf16_f32 %0, %1, %2" : "=v"(u2) : "v"(x1[0]), "v"(x1[1]));
        asm("v_cvt_pk_bf16_f32 %0, %1, %2" : "=v"(u3) : "v"(x1[2]), "v"(x1[3]));
        union { unsigned u[4]; bf16x8 v; } pk;
        pk.u[0] = u0; pk.u[1] = u1; pk.u[2] = u2; pk.u[3] = u3;
        *(bf16x8*)(sA[buf] + aL) = pk.v;
    };

    f32x4 acc[2][2];
#pragma unroll
    for (int i = 0; i < 2; ++i)
#pragma unroll
        for (int jn = 0; jn < 2; ++jn) acc[i][jn] = (f32x4){0.f, 0.f, 0.f, 0.f};

    const int NITER = N_ / 128;  // 16

    issueB(0, 0);
    f32x4 aCur0 = *(const f32x4*)(aSrc);
    f32x4 aCur1 = *(const f32x4*)(aSrc + 4);
    f32x4 aNxt0 = *(const f32x4*)(aSrc + 128);
    f32x4 aNxt1 = *(const f32x4*)(aSrc + 132);
    asm volatile("s_waitcnt vmcnt(2)" ::: "memory");
    cvtWrite(0, aCur0, aCur1);
    aCur0 = aNxt0; aCur1 = aNxt1;
    asm volatile("s_waitcnt lgkmcnt(0)" ::: "memory");

#pragma unroll
    for (int it = 0; it < NITER; ++it) {
        const int cur = it & 1, nxt = cur ^ 1;
        int outst = 0;
        if (it + 1 < NITER) { issueB(nxt, (it + 1) * 128); outst += 4; }
        if (it + 2 < NITER) {
            const float* s = aSrc + (it + 2) * 128;
            aNxt0 = *(const f32x4*)(s);
            aNxt1 = *(const f32x4*)(s + 4);
            outst += 2;
        }
        if (outst == 6)      asm volatile("s_waitcnt vmcnt(6)" ::: "memory");
        else if (outst == 4) asm volatile("s_waitcnt vmcnt(4)" ::: "memory");
        else                 asm volatile("s_waitcnt vmcnt(0)" ::: "memory");
        __builtin_amdgcn_sched_barrier(0);
        __builtin_amdgcn_s_barrier();

        const unsigned char* pA = sA[cur];
        const unsigned char* pB = sB[cur];
#pragma unroll
        for (int kk2 = 0; kk2 < 2; ++kk2) {
            const int kk = kg * 2 + kk2;
            bf16x8 a[2], bb[2];
#pragma unroll
            for (int i = 0; i < 2; ++i) {
                unsigned row = (unsigned)(i * 16 + lr);
                unsigned byte = row * 256 + (unsigned)(lh * 16 + kk * 64);
                byte ^= (row & 7u) << 4;
                a[i] = *(const bf16x8*)(pA + byte);
            }
#pragma unroll
            for (int jn = 0; jn < 2; ++jn) {
                unsigned d = (unsigned)(cg * 32 + jn * 16 + lr);
                unsigned byte = d * 256 + (unsigned)(lh * 16 + kk * 64);
                byte ^= (d & 7u) << 4;
                bb[jn] = *(const bf16x8*)(pB + byte);
            }
#pragma unroll
            for (int i = 0; i < 2; ++i)
#pragma unroll
                for (int jn = 0; jn < 2; ++jn)
                    acc[i][jn] = __builtin_amdgcn_mfma_f32_16x16x32_bf16(a[i], bb[jn], acc[i][jn], 0, 0, 0);
        }
        if (it + 1 < NITER) {
            cvtWrite(nxt, aCur0, aCur1);
            aCur0 = aNxt0; aCur1 = aNxt1;
        }
        asm volatile("s_waitcnt lgkmcnt(0)" ::: "memory");
        __builtin_amdgcn_sched_barrier(0);
        __builtin_amdgcn_s_barrier();
    }

    float* sO = (float*)sA;   // 32 x 128 f32 = 16 KB
    if (kg == 1) {
#pragma unroll
        for (int i = 0; i < 2; ++i)
#pragma unroll
            for (int jn = 0; jn < 2; ++jn)
#pragma unroll
                for (int r = 0; r < 4; ++r) {
                    int rowl = i * 16 + lh * 4 + r;
                    int d = cg * 32 + jn * 16 + lr;
                    sO[rowl * 128 + d] = acc[i][jn][r];
                }
    }
    __syncthreads();
    if (kg == 0) {
#pragma unroll
        for (int i = 0; i < 2; ++i) {
            float4 r4 = *(const float4*)(rsB + R0 + i * 16 + lh * 4);
            float rr[4] = {r4.x, r4.y, r4.z, r4.w};
#pragma unroll
            for (int r = 0; r < 4; ++r) {
                int rowl = i * 16 + lh * 4 + r;
#pragma unroll
                for (int jn = 0; jn < 2; ++jn) {
                    int d = cg * 32 + jn * 16 + lr;
                    float v = (acc[i][jn][r] + sO[rowl * 128 + d]) * rr[r];
                    out[((size_t)(b * N_ + R0 + rowl)) * D_ + d] = fmaxf(v, 0.f);
                }
            }
        }
    }
}

extern "C" void kernel_launch(void* const* d_in, const int* in_sizes, int n_in,
                              void* d_out, int out_size, void* d_ws, size_t ws_size,
                              hipStream_t stream) {
    const float* inputs = (const float*)d_in[0];   // [B,N,F]
    const float* adj    = (const float*)d_in[1];   // [B,N,N]
    const float* Wk     = (const float*)d_in[2];   // [F,D]
    const float* Wb     = (const float*)d_in[3];   // [D]
    float* out = (float*)d_out;

    char* ws = (char*)d_ws;
    float* rs          = (float*)ws;                          // 64 KB @ 0
    unsigned short* gt = (unsigned short*)(ws + (1 << 20));   // 4 MB  @ 1 MB
    unsigned short* Wt = (unsigned short*)(ws + (6 << 20));   // 32 KB @ 6 MB

    k_degwt<<<4096 + 8, 256, 0, stream>>>(adj, Wk, rs, Wt);
    k_feat <<<(B_ * N_) / 64, 256, 0, stream>>>(inputs, Wt, Wb, rs, gt);
    // MEASUREMENT ROUND: k_gcn launched 3x (idempotent). T_gcn = (dur - 55.8)/2.
    k_gcn  <<<B_ * (N_ / 32), 512, 0, stream>>>(adj, gt, rs, out);
    k_gcn  <<<B_ * (N_ / 32), 512, 0, stream>>>(adj, gt, rs, out);
    k_gcn  <<<B_ * (N_ / 32), 512, 0, stream>>>(adj, gt, rs, out);
}

// Round 11
// 54.463 us; speedup vs baseline: 1.9624x; 1.9624x over previous
//
#include <hip/hip_runtime.h>
#include <hip/hip_bf16.h>
#include <stdint.h>

#define B_ 8
#define N_ 2048
#define F_ 128
#define D_ 128

typedef short bf16x8 __attribute__((ext_vector_type(8)));
typedef float f32x4 __attribute__((ext_vector_type(4)));

__device__ __forceinline__ unsigned short f2bf(float f) {
    unsigned u = __float_as_uint(f);
    u += 0x7fffu + ((u >> 16) & 1u);
    return (unsigned short)(u >> 16);
}

// ---------------- Kernel 1: degrees -> rsqrt  (+ W transpose in tail blocks) ----------------
__global__ __launch_bounds__(256) void k_degwt(const float* __restrict__ adj,
                                               const float* __restrict__ W,
                                               float* __restrict__ rs,
                                               unsigned short* __restrict__ Wt) {
    if (blockIdx.x < 4096) {
        const int wave = threadIdx.x >> 6, lane = threadIdx.x & 63;
        const int row = blockIdx.x * 4 + wave;          // 0..B_*N_-1
        const float4* p = (const float4*)(adj + (size_t)row * N_);
        float s = 0.f;
#pragma unroll
        for (int j = 0; j < 8; ++j) {
            float4 v = p[j * 64 + lane];
            s += (v.x + v.y) + (v.z + v.w);
        }
#pragma unroll
        for (int m = 1; m < 64; m <<= 1) s += __shfl_xor(s, m, 64);
        if (lane == 0) rs[row] = (s > 0.f) ? (1.0f / sqrtf(s)) : 0.f;
    } else {
        int c = (blockIdx.x - 4096) * 256 + threadIdx.x;
        int d = c >> 4, f0 = (c & 15) * 8;
        union { bf16x8 v; unsigned short u[8]; } pk;
#pragma unroll
        for (int e = 0; e < 8; ++e) pk.u[e] = f2bf(W[(size_t)(f0 + e) * D_ + d]);
        *(bf16x8*)(Wt + (size_t)d * F_ + f0) = pk.v;
    }
}

// ---------------- Kernel 2: gt[b][d][m] = rs[m]*(X@W + bias)^T, bf16 (pre-scaled) ----------------
__global__ __launch_bounds__(256) void k_feat(const float* __restrict__ x,
                                              const unsigned short* __restrict__ Wt,
                                              const float* __restrict__ bias,
                                              const float* __restrict__ rs,
                                              unsigned short* __restrict__ gt) {
    __shared__ __align__(16) unsigned char sX[64 * 128 * 2];
    __shared__ __align__(16) unsigned char sW[128 * 128 * 2];
    const int t = threadIdx.x;
    const int R0 = blockIdx.x * 64;

#pragma unroll
    for (int j = 0; j < 8; ++j) {
        int c = j * 256 + t;
        unsigned L = (unsigned)c * 16u;
        unsigned lg = L ^ (((L >> 8) & 7u) << 4);
        const unsigned char* src = (const unsigned char*)Wt + lg;
        __builtin_amdgcn_global_load_lds(
            (const __attribute__((address_space(1))) void*)src,
            (__attribute__((address_space(3))) void*)(sW + L), 16, 0, 0);
    }
#pragma unroll
    for (int j = 0; j < 4; ++j) {
        int c = j * 256 + t;
        int row = c >> 4, sub = c & 15;
        const float4* src = (const float4*)(x + (size_t)(R0 + row) * F_ + sub * 8);
        float4 v0 = src[0], v1 = src[1];
        union { bf16x8 v; unsigned short u[8]; } pk;
        pk.u[0] = f2bf(v0.x); pk.u[1] = f2bf(v0.y); pk.u[2] = f2bf(v0.z); pk.u[3] = f2bf(v0.w);
        pk.u[4] = f2bf(v1.x); pk.u[5] = f2bf(v1.y); pk.u[6] = f2bf(v1.z); pk.u[7] = f2bf(v1.w);
        unsigned byte = (unsigned)(row * 256 + sub * 16);
        byte ^= ((byte >> 8) & 7u) << 4;
        *(bf16x8*)(sX + byte) = pk.v;
    }
    __syncthreads();

    const int w = t >> 6, l = t & 63, lr = l & 15, lh = l >> 4;
    f32x4 acc[8];
#pragma unroll
    for (int j = 0; j < 8; ++j) acc[j] = (f32x4){0.f, 0.f, 0.f, 0.f};

#pragma unroll
    for (int ks = 0; ks < 4; ++ks) {
        unsigned abyte = (unsigned)((w * 16 + lr) * 256 + lh * 16 + ks * 64);
        abyte ^= ((abyte >> 8) & 7u) << 4;
        bf16x8 a = *(const bf16x8*)(sX + abyte);
#pragma unroll
        for (int j = 0; j < 8; ++j) {
            unsigned bbyte = (unsigned)((j * 16 + lr) * 256 + lh * 16 + ks * 64);
            bbyte ^= ((bbyte >> 8) & 7u) << 4;
            bf16x8 bb = *(const bf16x8*)(sW + bbyte);
            acc[j] = __builtin_amdgcn_mfma_f32_16x16x32_bf16(a, bb, acc[j], 0, 0, 0);
        }
    }

    const int m0 = R0 + w * 16 + lh * 4;
    float4 r4 = *(const float4*)(rs + m0);
    float rr[4] = {r4.x, r4.y, r4.z, r4.w};
#pragma unroll
    for (int j = 0; j < 8; ++j) {
        int d = j * 16 + lr;
        float bv = bias[d];
#pragma unroll
        for (int r = 0; r < 4; ++r) {
            int m = m0 + r;
            int b = m >> 11, n = m & (N_ - 1);
            gt[((size_t)b * D_ + d) * N_ + n] = f2bf((acc[j][r] + bv) * rr[r]);
        }
    }
}

// ---------------- Kernel 3: out = relu(rs[n] * (adj @ gt^T)) ----------------
// 256 blocks (1/CU, batch==XCD), 512 thr. BM=64 BN=128 BK=64, NITER=32.
// 4 LDS buffers (24 KB each: A 8K + B 16K), prefetch depth 3, counted vmcnt
// (12 steady / 8 mid), A cvt+ds_write during MFMA phase. gt traffic halved vs BM=32.
#define BUFSZ (24 * 1024)
#define VM(n) asm volatile("s_waitcnt vmcnt(" #n ")" ::: "memory")
#define LGKM0 asm volatile("s_waitcnt lgkmcnt(0)" ::: "memory")
#define SCHED __builtin_amdgcn_sched_barrier(0)
#define BAR __builtin_amdgcn_s_barrier()

__global__ __launch_bounds__(512) void k_gcn(const float* __restrict__ adj,
                                             const unsigned short* __restrict__ gt,
                                             const float* __restrict__ rs,
                                             float* __restrict__ out) {
    __shared__ __align__(16) unsigned char sBuf[4 * BUFSZ];   // 96 KB

    const int bid = blockIdx.x;          // 256 blocks: bid&7 == XCD == batch
    const int b = bid & 7;
    const int R0 = (bid >> 3) * 64;

    const float* adjB = adj + (size_t)(b * N_ + R0) * N_;
    const unsigned short* gtB = gt + (size_t)b * D_ * N_;
    const float* rsB = rs + (size_t)b * N_;

    const int t = threadIdx.x;
    const int w = t >> 6, l = t & 63, lr = l & 15, lh = l >> 4;
    const int wr = w >> 2, wc = w & 3;   // wave tile: rows wr*32..+32, cols wc*32..+32

    // A: thread owns row t>>3, 8 fp32 at col (t&7)*8 within each 64-wide K-slice
    const float* aSrc = adjB + (size_t)(t >> 3) * N_ + (t & 7) * 8;
    const unsigned aRow = (unsigned)(t >> 3);
    unsigned aL = aRow * 128u + (unsigned)((t & 7) * 16);
    aL ^= ((aRow & 7u) << 4) ^ ((aRow & 8u) << 3);

    // B: 2 chunks/thread; linear LDS dest (DMA), inverse-swizzled global src
    const unsigned short* bSrc0;
    const unsigned short* bSrc1;
    unsigned bL0, bL1;
    {
        unsigned c0 = (unsigned)t, c1 = (unsigned)(512 + t);
        unsigned L0 = c0 * 16u, L1 = c1 * 16u;
        unsigned d0 = L0 >> 7, d1 = L1 >> 7;
        unsigned w0 = (L0 & 127u) ^ ((d0 & 7u) << 4) ^ ((d0 & 8u) << 3);
        unsigned w1 = (L1 & 127u) ^ ((d1 & 7u) << 4) ^ ((d1 & 8u) << 3);
        bSrc0 = gtB + (size_t)d0 * N_ + (w0 >> 1);
        bSrc1 = gtB + (size_t)d1 * N_ + (w1 >> 1);
        bL0 = 8192u + L0; bL1 = 8192u + L1;
    }

    // 4 A-reg slots (static names; slot = j&3)
    f32x4 aR0a, aR0b, aR1a, aR1b, aR2a, aR2b, aR3a, aR3b;

#define STAGE(J, S) do {                                                          \
    unsigned char* pBuf = sBuf + ((unsigned)(J) & 3u) * BUFSZ;                    \
    __builtin_amdgcn_global_load_lds(                                             \
        (const __attribute__((address_space(1))) void*)(bSrc0 + (J) * 64),       \
        (__attribute__((address_space(3))) void*)(pBuf + bL0), 16, 0, 0);        \
    __builtin_amdgcn_global_load_lds(                                             \
        (const __attribute__((address_space(1))) void*)(bSrc1 + (J) * 64),       \
        (__attribute__((address_space(3))) void*)(pBuf + bL1), 16, 0, 0);        \
    aR##S##a = *(const f32x4*)(aSrc + (J) * 64);                                  \
    aR##S##b = *(const f32x4*)(aSrc + (J) * 64 + 4);                              \
} while (0)

#define CVTW(J, S) do {                                                           \
    unsigned u0, u1, u2, u3;                                                      \
    asm("v_cvt_pk_bf16_f32 %0, %1, %2" : "=v"(u0) : "v"(aR##S##a[0]), "v"(aR##S##a[1])); \
    asm("v_cvt_pk_bf16_f32 %0, %1, %2" : "=v"(u1) : "v"(aR##S##a[2]), "v"(aR##S##a[3])); \
    asm("v_cvt_pk_bf16_f32 %0, %1, %2" : "=v"(u2) : "v"(aR##S##b[0]), "v"(aR##S##b[1])); \
    asm("v_cvt_pk_bf16_f32 %0, %1, %2" : "=v"(u3) : "v"(aR##S##b[2]), "v"(aR##S##b[3])); \
    union { unsigned uu[4]; bf16x8 v; } pk;                                       \
    pk.uu[0] = u0; pk.uu[1] = u1; pk.uu[2] = u2; pk.uu[3] = u3;                   \
    *(bf16x8*)(sBuf + ((unsigned)(J) & 3u) * BUFSZ + aL) = pk.v;                  \
} while (0)

#define MFMA_IT(IT) do {                                                          \
    const unsigned char* pA = sBuf + ((unsigned)(IT) & 3u) * BUFSZ;               \
    const unsigned char* pB = pA + 8192;                                          \
    _Pragma("unroll")                                                             \
    for (int kk = 0; kk < 2; ++kk) {                                              \
        bf16x8 a_[2], b_[2];                                                      \
        _Pragma("unroll")                                                         \
        for (int i = 0; i < 2; ++i) {                                             \
            unsigned row = (unsigned)(wr * 32 + i * 16 + lr);                     \
            unsigned byte = row * 128u + (unsigned)(kk * 64 + lh * 16);           \
            byte ^= ((row & 7u) << 4) ^ ((row & 8u) << 3);                        \
            a_[i] = *(const bf16x8*)(pA + byte);                                  \
        }                                                                         \
        _Pragma("unroll")                                                         \
        for (int jn = 0; jn < 2; ++jn) {                                          \
            unsigned d = (unsigned)(wc * 32 + jn * 16 + lr);                      \
            unsigned byte = d * 128u + (unsigned)(kk * 64 + lh * 16);             \
            byte ^= ((d & 7u) << 4) ^ ((d & 8u) << 3);                            \
            b_[jn] = *(const bf16x8*)(pB + byte);                                 \
        }                                                                         \
        _Pragma("unroll")                                                         \
        for (int i = 0; i < 2; ++i)                                               \
            _Pragma("unroll")                                                     \
            for (int jn = 0; jn < 2; ++jn)                                        \
                acc[i][jn] = __builtin_amdgcn_mfma_f32_16x16x32_bf16(             \
                    a_[i], b_[jn], acc[i][jn], 0, 0, 0);                          \
    }                                                                             \
} while (0)

    f32x4 acc[2][2];
#pragma unroll
    for (int i = 0; i < 2; ++i)
#pragma unroll
        for (int jn = 0; jn < 2; ++jn) acc[i][jn] = (f32x4){0.f, 0.f, 0.f, 0.f};

    // prologue: stages 0,1,2 in flight; A(0) cvt+written
    STAGE(0, 0);
    STAGE(1, 1);
    STAGE(2, 2);
    VM(8);            // stage(0) landed (B0 in LDS, A0 regs)
    SCHED;
    CVTW(0, 0);
    LGKM0; SCHED;

    // main: it = it4*4 + k, it4 = 0..6 (it 0..27), steady counts 12/8
    for (int it4 = 0; it4 < 7; ++it4) {
        const int itb = it4 * 4;
        // k=0: stage slot 3, cvt slot 1
        STAGE(itb + 3, 3); VM(12); SCHED; BAR;
        MFMA_IT(0);
        VM(8); SCHED; CVTW(itb + 1, 1); LGKM0; SCHED; BAR;
        // k=1: stage slot 0, cvt slot 2
        STAGE(itb + 4, 0); VM(12); SCHED; BAR;
        MFMA_IT(1);
        VM(8); SCHED; CVTW(itb + 2, 2); LGKM0; SCHED; BAR;
        // k=2: stage slot 1, cvt slot 3
        STAGE(itb + 5, 1); VM(12); SCHED; BAR;
        MFMA_IT(2);
        VM(8); SCHED; CVTW(itb + 3, 3); LGKM0; SCHED; BAR;
        // k=3: stage slot 2, cvt slot 0
        STAGE(itb + 6, 2); VM(12); SCHED; BAR;
        MFMA_IT(3);
        VM(8); SCHED; CVTW(itb + 4, 0); LGKM0; SCHED; BAR;
    }
    // tail: it = 28..31 (28&3=0)
    STAGE(31, 3); VM(12); SCHED; BAR;
    MFMA_IT(28);
    VM(8); SCHED; CVTW(29, 1); LGKM0; SCHED; BAR;

    VM(8); SCHED; BAR;
    MFMA_IT(29);
    VM(4); SCHED; CVTW(30, 2); LGKM0; SCHED; BAR;

    VM(4); SCHED; BAR;
    MFMA_IT(30);
    VM(0); SCHED; CVTW(31, 3); LGKM0; SCHED; BAR;

    BAR;
    MFMA_IT(31);

    // epilogue: rs[n]*acc, relu, store
#pragma unroll
    for (int i = 0; i < 2; ++i) {
        float4 r4 = *(const float4*)(rsB + R0 + wr * 32 + i * 16 + lh * 4);
        float rr[4] = {r4.x, r4.y, r4.z, r4.w};
#pragma unroll
        for (int r = 0; r < 4; ++r) {
            int rowl = wr * 32 + i * 16 + lh * 4 + r;
#pragma unroll
            for (int jn = 0; jn < 2; ++jn) {
                int d = wc * 32 + jn * 16 + lr;
                float v = acc[i][jn][r] * rr[r];
                out[((size_t)(b * N_ + R0 + rowl)) * D_ + d] = fmaxf(v, 0.f);
            }
        }
    }
}

extern "C" void kernel_launch(void* const* d_in, const int* in_sizes, int n_in,
                              void* d_out, int out_size, void* d_ws, size_t ws_size,
                              hipStream_t stream) {
    const float* inputs = (const float*)d_in[0];   // [B,N,F]
    const float* adj    = (const float*)d_in[1];   // [B,N,N]
    const float* Wk     = (const float*)d_in[2];   // [F,D]
    const float* Wb     = (const float*)d_in[3];   // [D]
    float* out = (float*)d_out;

    char* ws = (char*)d_ws;
    float* rs          = (float*)ws;                          // 64 KB @ 0
    unsigned short* gt = (unsigned short*)(ws + (1 << 20));   // 4 MB  @ 1 MB
    unsigned short* Wt = (unsigned short*)(ws + (6 << 20));   // 32 KB @ 6 MB

    k_degwt<<<4096 + 8, 256, 0, stream>>>(adj, Wk, rs, Wt);
    k_feat <<<(B_ * N_) / 64, 256, 0, stream>>>(inputs, Wt, Wb, rs, gt);
    k_gcn  <<<256, 512, 0, stream>>>(adj, gt, rs, out);
}